// Round 2
// baseline (212.244 us; speedup 1.0000x reference)
//
#include <hip/hip_runtime.h>
#include <cmath>
#include <cstring>
#include <vector>
#include <algorithm>

// ---------------------------------------------------------------------------
// Host-side precompute: u = conj(A)·ones for Candan's DFrFT, N=128, a=0.5.
// Only the even-parity (C2) eigenvectors contribute (ones is even-symmetric).
// u[h] = sum_{m=0..64} i^m * q_m[h] * (sum_n q_m[n]),  q_m = m-th DESCENDING
// even eigenvector = P·[vc[:,64-m]; 0].
// ---------------------------------------------------------------------------

struct UV { float ur[128]; float ui[128]; };
static UV g_uv;

namespace {

constexpr int NN = 128;

void matmul_d(const std::vector<double>& A, const std::vector<double>& B,
              std::vector<double>& C, int n) {
  for (int i = 0; i < n; ++i)
    for (int j = 0; j < n; ++j) {
      double s = 0.0;
      for (int k = 0; k < n; ++k) s += A[(size_t)i*n+k] * B[(size_t)k*n+j];
      C[(size_t)i*n+j] = s;
    }
}

// Cyclic Jacobi eigensolver for symmetric A (row-major n x n, destroyed).
// V's columns become eigenvectors; lam the eigenvalues (unsorted).
void jacobi_eigh(std::vector<double>& A, int n, std::vector<double>& V,
                 std::vector<double>& lam) {
  V.assign((size_t)n*n, 0.0);
  for (int i = 0; i < n; ++i) V[(size_t)i*n+i] = 1.0;
  for (int sweep = 0; sweep < 200; ++sweep) {
    double off = 0.0;
    for (int p = 0; p < n; ++p)
      for (int q = p+1; q < n; ++q) off += A[(size_t)p*n+q]*A[(size_t)p*n+q];
    if (off < 1e-24) break;
    for (int p = 0; p < n-1; ++p)
      for (int q = p+1; q < n; ++q) {
        double apq = A[(size_t)p*n+q];
        if (std::fabs(apq) < 1e-300) continue;
        double app = A[(size_t)p*n+p], aqq = A[(size_t)q*n+q];
        double tau = (aqq - app) / (2.0*apq);
        double t = (tau >= 0 ? 1.0 : -1.0) / (std::fabs(tau) + std::sqrt(1.0 + tau*tau));
        double c = 1.0/std::sqrt(1.0 + t*t), s = t*c;
        for (int k = 0; k < n; ++k) {           // A <- A*J
          double akp = A[(size_t)k*n+p], akq = A[(size_t)k*n+q];
          A[(size_t)k*n+p] = c*akp - s*akq;
          A[(size_t)k*n+q] = s*akp + c*akq;
        }
        for (int k = 0; k < n; ++k) {           // A <- J^T*A
          double apk = A[(size_t)p*n+k], aqk = A[(size_t)q*n+k];
          A[(size_t)p*n+k] = c*apk - s*aqk;
          A[(size_t)q*n+k] = s*apk + c*aqk;
        }
        for (int k = 0; k < n; ++k) {           // V <- V*J
          double vkp = V[(size_t)k*n+p], vkq = V[(size_t)k*n+q];
          V[(size_t)k*n+p] = c*vkp - s*vkq;
          V[(size_t)k*n+q] = s*vkp + c*vkq;
        }
      }
  }
  lam.resize(n);
  for (int i = 0; i < n; ++i) lam[i] = A[(size_t)i*n+i];
}

bool init_uv() {
  const int n = NN, r = NN/2;                 // N even: even=1, r=64
  const double c = 1.0/std::sqrt(2.0);
  const double PI = 3.14159265358979323846;
  std::vector<double> S((size_t)n*n, 0.0), P((size_t)n*n, 0.0);
  for (int i = 0; i < n; ++i) {               // S = circ([0,1,0..0,1]) + diag(2cos)
    S[(size_t)i*n+i] = 2.0*std::cos(2.0*PI*i/n);
    S[(size_t)i*n + (i+1)%n] += 1.0;
    S[(size_t)i*n + (i-1+n)%n] += 1.0;
  }
  P[0] = 1.0;
  for (int i = 1; i <= r-1; ++i) { P[(size_t)i*n+i] = c;  P[(size_t)i*n + (n-i)] = c; }
  P[(size_t)r*n+r] = 1.0;
  for (int i = r+1; i < n; ++i)  { P[(size_t)i*n+i] = -c; P[(size_t)i*n + (n-i)] = c; }
  std::vector<double> Pt((size_t)n*n), T((size_t)n*n), CS((size_t)n*n);
  for (int i = 0; i < n; ++i)
    for (int j = 0; j < n; ++j) Pt[(size_t)i*n+j] = P[(size_t)j*n+i];
  matmul_d(P, S, T, n);
  matmul_d(T, Pt, CS, n);
  const int m = r + 1;                        // 65x65 even block
  std::vector<double> C2((size_t)m*m);
  for (int i = 0; i < m; ++i)
    for (int j = 0; j < m; ++j) C2[(size_t)i*m+j] = CS[(size_t)i*n+j];
  std::vector<double> V, lam;
  jacobi_eigh(C2, m, V, lam);
  std::vector<int> idx(m);
  for (int i = 0; i < m; ++i) idx[i] = i;
  std::sort(idx.begin(), idx.end(), [&](int a, int b){ return lam[a] < lam[b]; });
  double ure[NN] = {0}, uim[NN] = {0};
  for (int mm = 0; mm < m; ++mm) {
    int col = idx[m-1-mm];                    // mm-th in DESCENDING order
    double q[NN];
    q[0] = V[(size_t)0*m+col];
    for (int j = 1; j <= r-1; ++j) q[j] = c * V[(size_t)j*m+col];
    q[r] = V[(size_t)r*m+col];
    for (int j = r+1; j < n; ++j)  q[j] = c * V[(size_t)(n-j)*m+col];
    double ssum = 0.0;
    for (int j = 0; j < n; ++j) ssum += q[j];
    switch (mm & 3) {                         // weight i^m
      case 0: for (int h = 0; h < n; ++h) ure[h] += q[h]*ssum; break;
      case 1: for (int h = 0; h < n; ++h) uim[h] += q[h]*ssum; break;
      case 2: for (int h = 0; h < n; ++h) ure[h] -= q[h]*ssum; break;
      case 3: for (int h = 0; h < n; ++h) uim[h] -= q[h]*ssum; break;
    }
  }
  for (int h = 0; h < n; ++h) { g_uv.ur[h] = (float)ure[h]; g_uv.ui[h] = (float)uim[h]; }
  return true;
}

bool g_inited = init_uv();

} // namespace

// ---------------------------------------------------------------------------
// GPU kernels
// ---------------------------------------------------------------------------

// Transpose 64x64 weights into d_ws so the main loop can read contiguous
// o-rows with wave-uniform s_load_dwordx16.
__global__ __launch_bounds__(256) void transpose_w_kernel(
    const float* __restrict__ wr, const float* __restrict__ wi,
    float* __restrict__ wTr, float* __restrict__ wTi) {
  int t = blockIdx.x * 256 + threadIdx.x;     // 4096 total
  if (t < 4096) {
    int o = t >> 6, i = t & 63;
    wTr[i*64 + o] = wr[t];
    wTi[i*64 + o] = wi[t];
  }
}

// Each block: one (b, h-row) => 128 positions, all 64 output channels.
// 4 waves; wave w owns outputs [16w, 16w+16); each lane owns 2 positions.
__global__ __launch_bounds__(256) void spec_main_kernel(
    const float* __restrict__ x,
    const float* __restrict__ wTr, const float* __restrict__ wTi,
    const float* __restrict__ br, const float* __restrict__ bi,
    float* __restrict__ out, UV uv) {
  __shared__ float xs[64][128];               // 32 KB: x[b, :, hrow, :]
  const int tid  = threadIdx.x;
  const int bid  = blockIdx.x;
  const int b    = bid >> 7;
  const int hrow = bid & 127;
  const long long pos0 = (long long)hrow << 7;
  const float* xb = x + ((long long)b << 20) + pos0;   // + i*16384 per channel

  // Stage x tile: 8192 floats as 2048 float4, coalesced.
#pragma unroll
  for (int k = 0; k < 8; ++k) {
    int q  = tid + (k << 8);
    int i  = q >> 5;
    int pw = (q & 31) << 2;
    float4 v = *(const float4*)(xb + (long long)i * 16384 + pw);
    *(float4*)&xs[i][pw] = v;
  }
  __syncthreads();

  const int lane = tid & 63;
  const int o0   = __builtin_amdgcn_readfirstlane((tid >> 6) << 4);
  const int w0   = lane << 1;                 // two adjacent positions per lane

  // Rank-1 bias init: bias[o,h,w] = bc[o]*u[h]*u[w]
  const float uhr = uv.ur[hrow], uhi = uv.ui[hrow];
  const float v0r = uv.ur[w0],   v0i = uv.ui[w0];
  const float v1r = uv.ur[w0+1], v1i = uv.ui[w0+1];
  const float g0r = uhr*v0r - uhi*v0i, g0i = uhr*v0i + uhi*v0r;
  const float g1r = uhr*v1r - uhi*v1i, g1i = uhr*v1i + uhi*v1r;

  float accr[16][2], acci[16][2];
#pragma unroll
  for (int oo = 0; oo < 16; ++oo) {
    float bro = br[o0+oo], bio = bi[o0+oo];
    accr[oo][0] = bro*g0r - bio*g0i;  acci[oo][0] = bro*g0i + bio*g0r;
    accr[oo][1] = bro*g1r - bio*g1i;  acci[oo][1] = bro*g1i + bio*g1r;
  }

  // Main: y[o,p] += sum_i w[o,i] * x[i,p]; weights via uniform scalar loads.
  for (int i = 0; i < 64; ++i) {
    float2 xv = *(const float2*)&xs[i][w0];
    const float* wrp = wTr + (i << 6) + o0;
    const float* wip = wTi + (i << 6) + o0;
#pragma unroll
    for (int oo = 0; oo < 16; ++oo) {
      float wr = wrp[oo], wi = wip[oo];
      accr[oo][0] += wr*xv.x;  accr[oo][1] += wr*xv.y;
      acci[oo][0] += wi*xv.x;  acci[oo][1] += wi*xv.y;
    }
  }

  // Store: out[(part*16 + b)*64 + o][pos], float2 per (o, part).
  long long baseR = (((long long)(b*64 + o0)) << 14) + pos0 + w0;
  long long baseI = baseR + ((long long)(16*64) << 14);
#pragma unroll
  for (int oo = 0; oo < 16; ++oo) {
    *(float2*)&out[baseR + ((long long)oo << 14)] = make_float2(accr[oo][0], accr[oo][1]);
    *(float2*)&out[baseI + ((long long)oo << 14)] = make_float2(acci[oo][0], acci[oo][1]);
  }
}

extern "C" void kernel_launch(void* const* d_in, const int* in_sizes, int n_in,
                              void* d_out, int out_size, void* d_ws, size_t ws_size,
                              hipStream_t stream) {
  (void)in_sizes; (void)n_in; (void)out_size; (void)ws_size; (void)g_inited;
  const float* x  = (const float*)d_in[0];
  const float* wr = (const float*)d_in[1];
  const float* wi = (const float*)d_in[2];
  const float* br = (const float*)d_in[3];
  const float* bi = (const float*)d_in[4];
  float* out = (float*)d_out;
  float* wTr = (float*)d_ws;                  // 16 KB
  float* wTi = wTr + 4096;                    // 16 KB

  transpose_w_kernel<<<16, 256, 0, stream>>>(wr, wi, wTr, wTi);
  spec_main_kernel<<<2048, 256, 0, stream>>>(x, wTr, wTi, br, bi, out, g_uv);
}